// Round 20
// baseline (17.460 us; speedup 1.0000x reference)
//
#include <hip/hip_runtime.h>
#include <hip/hip_bf16.h>
#include <math.h>

// B=4, T=S=512, M=N=512, H=128
#define KDIM 512
#define HDIM 128
#define SDIM 512
#define TOTAL_ROWS 2048
#define INV_SCALE 0.04419417382415922f   // 1/sqrt(512)

// score[b,t,s] = a'[b,t] + c'[b,s]  (both pre-scaled)
// H-SPLIT partials (tanh is per-h, so h-range sums are independent):
//   ws[0:2048)    a' partial, h in [0,64)     (query)
//   ws[2048:4096) a' partial, h in [64,128)
//   ws[4096:6144) c' partial, h in [0,64)     (keys)
//   ws[6144:8192) c' partial, h in [64,128)
// D1: 512 blocks x 256 thr = 2 blocks/CU co-resident (serial phases of the two
//     blocks overlap); W traffic unchanged vs r13 (each block reads a 128KB W slice).
// D2: outer adds the four partials.

typedef __attribute__((ext_vector_type(8))) short bf16x8;   // 8 bf16 = 4 VGPRs
typedef __attribute__((ext_vector_type(4))) float f32x4;    // MFMA accumulator

__device__ __forceinline__ float fast_tanh(float x) {
    // tanh(x) = 1 - 2/(e^{2x}+1); ~1e-7 abs error, graceful at +/-inf
    float e = __expf(2.0f * x);
    return 1.0f - 2.0f / (e + 1.0f);
}
__device__ __forceinline__ unsigned short bfbits(float x) {
    return __builtin_bit_cast(unsigned short, __float2bfloat16(x));
}
__device__ __forceinline__ bf16x8 cvt8(const float4 p, const float4 q) {
    bf16x8 r;
    r[0] = (short)bfbits(p.x); r[1] = (short)bfbits(p.y);
    r[2] = (short)bfbits(p.z); r[3] = (short)bfbits(p.w);
    r[4] = (short)bfbits(q.x); r[5] = (short)bfbits(q.y);
    r[6] = (short)bfbits(q.z); r[7] = (short)bfbits(q.w);
    return r;
}

// 512 blocks x 256 thr (4 waves). blk<256: query; blk>=256: keys.
// Within a side: rt = (blk&255)>>1 (row-tile of 16), hh = blk&1 (h-half of 64).
// Wave = one 16-h tile: h0 = hh*64 + wave*16. MFMA 16x16x32_bf16 with the
// r11/r13-verified k-bijection: lane-group g owns k-slots {t*32+g*4..+3} u
// {t*32+16+g*4..+3}; f32 W half-frag float4 loads cover FULL 64B lines.
// A staged bf16 in LDS, granule (t*4+g) XOR-swizzled by row&7 (conflict-free).
// C layout: col = lane&15 (h), row = g*4 + reg  ->  acc[r] = X[row0+g*4+r]·W[h0+c16].
__global__ __launch_bounds__(256, 2) void proj_kernel(
    const float* __restrict__ query, const float* __restrict__ keys,
    const float* __restrict__ W1, const float* __restrict__ W2,
    const float* __restrict__ v, float* __restrict__ ws)
{
    const int blk = blockIdx.x;
    const bool is_keys = (blk >= 256);
    const int local = blk & 255;
    const int rt = local >> 1;           // row-tile 0..127
    const int hh = local & 1;            // h-half 0/1
    const int row0 = rt * 16;
    const float* __restrict__ X  = is_keys ? keys : query;
    const float* __restrict__ Wf = is_keys ? W1 : W2;
    const float* __restrict__ vv = v + (is_keys ? HDIM : 0);
    float* __restrict__ outp = ws + (is_keys ? 4096 : 0) + hh * 2048;

    __shared__ __align__(16) unsigned short sm_x[16 * KDIM];  // 16 KB bf16
    __shared__ float sm_p[4][16];

    const int tid  = threadIdx.x;        // 0..255
    const int wave = tid >> 6;           // 0..3
    const int lane = tid & 63;

    // ---- Stage X tile: 16 rows x 512 k = 2048 float4; 8/thread, coalesced. ----
    {
        const float4* __restrict__ xsrc = (const float4*)(X + (size_t)row0 * KDIM);
        #pragma unroll
        for (int i = 0; i < 8; ++i) {
            const int f   = tid + i * 256;   // row*128 + fr
            const int row = f >> 7;
            const int fr  = f & 127;
            const float4 xv = xsrc[f];
            ushort4 o;
            o.x = bfbits(xv.x); o.y = bfbits(xv.y);
            o.z = bfbits(xv.z); o.w = bfbits(xv.w);
            const int s    = fr >> 3;        // 32-k step 0..15
            const int off4 = fr & 7;
            const int g    = off4 & 3;       // k-group
            const int half = off4 >> 2;      // 0: k-off 0-15, 1: 16-31
            char* dst = (char*)sm_x + row * 1024
                      + (((s * 4 + g) ^ (row & 7)) << 4) + half * 8;
            *(ushort4*)dst = o;
        }
    }
    __syncthreads();

    const int c16 = lane & 15;
    const int g   = lane >> 4;
    const int h0  = hh * 64 + wave * 16;
    const float* __restrict__ wrow = Wf + (size_t)(h0 + c16) * KDIM + g * 4;
    const char* __restrict__ arow = (const char*)sm_x + c16 * 1024;
    const int swz = c16 & 7;

    f32x4 acc = {0.0f, 0.0f, 0.0f, 0.0f};
    #pragma unroll 4
    for (int t = 0; t < 16; ++t) {
        const float4 b0 = *(const float4*)(wrow + t * 32);        // k t*32+g*4..+3
        const float4 b1 = *(const float4*)(wrow + t * 32 + 16);   // k t*32+16+g*4..+3
        const bf16x8 a = *(const bf16x8*)(arow + (((t * 4 + g) ^ swz) << 4));
        acc = __builtin_amdgcn_mfma_f32_16x16x32_bf16(a, cvt8(b0, b1), acc, 0, 0, 0);
    }

    // acc[r] = dot(X[row0+g*4+r], W[h0+c16]); weight, tanh, reduce over 16 h-cols.
    const float vh = vv[h0 + c16];
    #pragma unroll
    for (int r = 0; r < 4; ++r) {
        float s = vh * fast_tanh(acc[r]);
        s += __shfl_xor(s, 1, 64);   // reduce over c16 (lane bits 0-3)
        s += __shfl_xor(s, 2, 64);
        s += __shfl_xor(s, 4, 64);
        s += __shfl_xor(s, 8, 64);
        if (c16 == 0) sm_p[wave][g * 4 + r] = s;
    }
    __syncthreads();

    if (tid < 16) {
        const float s = sm_p[0][tid] + sm_p[1][tid] + sm_p[2][tid] + sm_p[3][tid];
        outp[row0 + tid] = s * INV_SCALE;   // h-half partial
    }
}

// 256 blocks x 256 thr; block = 8 bt-rows. Adds the four H-partials.
__global__ __launch_bounds__(256) void outer_kernel(
    const float* __restrict__ ws, float* __restrict__ out)
{
    const int r0  = blockIdx.x * 8;
    const int b   = r0 >> 9;
    const int col = threadIdx.x & 127;
    const int rh  = threadIdx.x >> 7;   // 0/1

    const float4 c0 = ((const float4*)(ws + 4096 + (size_t)b * SDIM))[col];
    const float4 c1 = ((const float4*)(ws + 6144 + (size_t)b * SDIM))[col];
    float4 c;
    c.x = c0.x + c1.x; c.y = c0.y + c1.y; c.z = c0.z + c1.z; c.w = c0.w + c1.w;

    #pragma unroll
    for (int rp = 0; rp < 4; ++rp) {
        const int row = r0 + rp * 2 + rh;
        const float a = ws[row] + ws[2048 + row];
        float4 o;
        o.x = a + c.x; o.y = a + c.y; o.z = a + c.z; o.w = a + c.w;
        ((float4*)out)[(size_t)row * (SDIM / 4) + col] = o;
    }
}

extern "C" void kernel_launch(void* const* d_in, const int* in_sizes, int n_in,
                              void* d_out, int out_size, void* d_ws, size_t ws_size,
                              hipStream_t stream) {
    const float* query = (const float*)d_in[0];  // (4,512,512)
    const float* keys  = (const float*)d_in[1];  // (4,512,512)
    const float* W1    = (const float*)d_in[2];  // (128,512)
    const float* W2    = (const float*)d_in[3];  // (128,512)
    const float* v     = (const float*)d_in[4];  // (1,256)
    float* out = (float*)d_out;                  // (4,512,512) f32
    float* ws  = (float*)d_ws;                   // 8192 floats of partials

    proj_kernel<<<512, 256, 0, stream>>>(query, keys, W1, W2, v, ws);
    outer_kernel<<<256, 256, 0, stream>>>(ws, out);
}

// Round 21
// 16.993 us; speedup vs baseline: 1.0275x; 1.0275x over previous
//
#include <hip/hip_runtime.h>
#include <hip/hip_bf16.h>
#include <math.h>

// B=4, T=S=512, M=N=512, H=128
#define KDIM 512
#define HDIM 128
#define SDIM 512
#define TOTAL_ROWS 2048
#define INV_SCALE 0.04419417382415922f   // 1/sqrt(512)

// score[b,t,s] = a'[b,t] + c'[b,s]  (both pre-scaled)
// ws: [0,2048) a' f32; [2048,4096) c' f32.
// D1: proj both sides, 256 blocks x 512 thr, K-half software-pipelined staging.
// D2: outer broadcast-add.
// CHAMPION (r17, 16.94 us). Session ledger: MFMA+k-bijection proj (no W pre-pass),
// 2-dispatch structure. Falsified alternatives: VALU-FMA proj (r2: 21), wcvt
// pre-pass (r10: 18.6), 8-row blocks (r11: 25), half-chip phases (r12: 22),
// no-LDS direct (r14: 23.6), 2x occupancy (r15: 17.3), W reg-preload (r19: 17.4),
// H-split 2 blk/CU (r20: 17.5), global-barrier fusion (r4: 45, r16: 37.7).

typedef __attribute__((ext_vector_type(8))) short bf16x8;   // 8 bf16 = 4 VGPRs
typedef __attribute__((ext_vector_type(4))) float f32x4;    // MFMA accumulator

__device__ __forceinline__ float fast_tanh(float x) {
    // tanh(x) = 1 - 2/(e^{2x}+1); ~1e-7 abs error, graceful at +/-inf
    float e = __expf(2.0f * x);
    return 1.0f - 2.0f / (e + 1.0f);
}
__device__ __forceinline__ unsigned short bfbits(float x) {
    return __builtin_bit_cast(unsigned short, __float2bfloat16(x));
}
__device__ __forceinline__ bf16x8 cvt8(const float4 p, const float4 q) {
    bf16x8 r;
    r[0] = (short)bfbits(p.x); r[1] = (short)bfbits(p.y);
    r[2] = (short)bfbits(p.z); r[3] = (short)bfbits(p.w);
    r[4] = (short)bfbits(q.x); r[5] = (short)bfbits(q.y);
    r[6] = (short)bfbits(q.z); r[7] = (short)bfbits(q.w);
    return r;
}

// Stage one K-half of the X tile into LDS with the k-bijection granule layout.
__device__ __forceinline__ void stage_half(
    unsigned short* sm_x, const float4 xv, int fhalf, int halfsel)
{
    const int row  = fhalf >> 6;
    const int fr   = fhalf & 63;
    const int s    = (fr >> 3) + halfsel * 8;   // global 32-k step
    const int off4 = fr & 7;
    const int g    = off4 & 3;
    const int half = off4 >> 2;
    ushort4 o;
    o.x = bfbits(xv.x); o.y = bfbits(xv.y);
    o.z = bfbits(xv.z); o.w = bfbits(xv.w);
    char* dst = (char*)sm_x + row * 1024 + (((s * 4 + g) ^ (row & 7)) << 4) + half * 8;
    *(ushort4*)dst = o;
}

// 256 blocks x 512 thr (8 waves): blk<128 query w/ W2 -> ws[0:2048);
// blk>=128 keys w/ W1 -> ws[2048:4096). 16 rows/block; wave = h-tile h0=16*wave.
// K-half pipelined: stage k[0,256) -> sync -> issue k[256,512) loads ->
// MFMA steps 0-7 -> write+sync -> MFMA steps 8-15.
// k-bijection (r11/r13-verified): lane-group g owns k-slots {t*32+g*4..+3} u
// {t*32+16+g*4..+3}; f32 W half-frag float4 loads cover FULL 64B lines.
// C layout: col = lane&15 (h), row = g*4 + reg  ->  acc[r] = X[row0+g*4+r]·W[h0+c16].
__global__ __launch_bounds__(512) void proj_kernel(
    const float* __restrict__ query, const float* __restrict__ keys,
    const float* __restrict__ W1, const float* __restrict__ W2,
    const float* __restrict__ v, float* __restrict__ ws)
{
    const int blk = blockIdx.x;
    const bool is_keys = (blk >= 128);
    const float* __restrict__ X  = is_keys ? keys : query;
    const float* __restrict__ Wf = is_keys ? W1 : W2;
    const float* __restrict__ vv = v + (is_keys ? HDIM : 0);
    float* __restrict__ out = ws + (is_keys ? TOTAL_ROWS : 0);
    const int row0 = (blk & 127) * 16;

    __shared__ __align__(16) unsigned short sm_x[16 * KDIM];  // 16 KB bf16
    __shared__ float sm_p[8][16];

    const int tid  = threadIdx.x;
    const int wave = tid >> 6;
    const int lane = tid & 63;

    const float4* __restrict__ xsrc = (const float4*)(X + (size_t)row0 * KDIM);

    // ---- Phase A stage: k in [0,256) for all 16 rows (1024 float4, 2/thread). ----
    {
        const int f0 = tid, f1 = tid + 512;
        const float4 xa0 = xsrc[(f0 >> 6) * 128 + (f0 & 63)];
        const float4 xa1 = xsrc[(f1 >> 6) * 128 + (f1 & 63)];
        stage_half(sm_x, xa0, f0, 0);
        stage_half(sm_x, xa1, f1, 0);
    }
    __syncthreads();

    // ---- Issue Phase B loads NOW (k in [256,512)); consumed after loop A. ----
    const int f0 = tid, f1 = tid + 512;
    const float4 xb0 = xsrc[(f0 >> 6) * 128 + 64 + (f0 & 63)];
    const float4 xb1 = xsrc[(f1 >> 6) * 128 + 64 + (f1 & 63)];

    const int c16 = lane & 15;
    const int g   = lane >> 4;
    const int h0  = wave * 16;
    const float* __restrict__ wrow = Wf + (size_t)(h0 + c16) * KDIM + g * 4;
    const char* __restrict__ arow = (const char*)sm_x + c16 * 1024;
    const int swz = c16 & 7;

    f32x4 acc = {0.0f, 0.0f, 0.0f, 0.0f};

    // ---- Loop A: K-steps 0-7 (k 0-255) — covers the Phase B loads in flight. ----
    #pragma unroll
    for (int t = 0; t < 8; ++t) {
        const float4 b0 = *(const float4*)(wrow + t * 32);        // k t*32+g*4..+3
        const float4 b1 = *(const float4*)(wrow + t * 32 + 16);   // k t*32+16+g*4..+3
        const bf16x8 a = *(const bf16x8*)(arow + (((t * 4 + g) ^ swz) << 4));
        acc = __builtin_amdgcn_mfma_f32_16x16x32_bf16(a, cvt8(b0, b1), acc, 0, 0, 0);
    }

    // ---- Phase B stage (disjoint LDS region; one sync before reads). ----
    stage_half(sm_x, xb0, f0, 1);
    stage_half(sm_x, xb1, f1, 1);
    __syncthreads();

    // ---- Loop B: K-steps 8-15 (k 256-511). ----
    #pragma unroll
    for (int t = 8; t < 16; ++t) {
        const float4 b0 = *(const float4*)(wrow + t * 32);
        const float4 b1 = *(const float4*)(wrow + t * 32 + 16);
        const bf16x8 a = *(const bf16x8*)(arow + (((t * 4 + g) ^ swz) << 4));
        acc = __builtin_amdgcn_mfma_f32_16x16x32_bf16(a, cvt8(b0, b1), acc, 0, 0, 0);
    }

    // acc[r] = dot(X[row0+g*4+r], W[h0+c16]); weight by v, tanh, reduce over h.
    const float vh = vv[h0 + c16];
    #pragma unroll
    for (int r = 0; r < 4; ++r) {
        float s = vh * fast_tanh(acc[r]);
        s += __shfl_xor(s, 1, 64);   // reduce over h-columns (lane bits 0-3)
        s += __shfl_xor(s, 2, 64);
        s += __shfl_xor(s, 4, 64);
        s += __shfl_xor(s, 8, 64);
        if (c16 == 0) sm_p[wave][g * 4 + r] = s;
    }
    __syncthreads();

    if (tid < 16) {
        float s = 0.0f;
        #pragma unroll
        for (int w = 0; w < 8; ++w) s += sm_p[w][tid];
        out[row0 + tid] = s * INV_SCALE;
    }
}

// 256 blocks x 256 thr; block = 8 bt-rows (single batch each). c' row stays L1-hot.
__global__ __launch_bounds__(256) void outer_kernel(
    const float* __restrict__ ws, float* __restrict__ out)
{
    const int r0  = blockIdx.x * 8;
    const int b   = r0 >> 9;
    const float4* __restrict__ c4 = (const float4*)(ws + TOTAL_ROWS + (size_t)b * SDIM);
    const int col = threadIdx.x & 127;
    const int rh  = threadIdx.x >> 7;   // 0/1

    #pragma unroll
    for (int rp = 0; rp < 4; ++rp) {
        const int row = r0 + rp * 2 + rh;
        const float a = ws[row];
        const float4 c = c4[col];
        float4 o;
        o.x = a + c.x; o.y = a + c.y; o.z = a + c.z; o.w = a + c.w;
        ((float4*)out)[(size_t)row * (SDIM / 4) + col] = o;
    }
}

extern "C" void kernel_launch(void* const* d_in, const int* in_sizes, int n_in,
                              void* d_out, int out_size, void* d_ws, size_t ws_size,
                              hipStream_t stream) {
    const float* query = (const float*)d_in[0];  // (4,512,512)
    const float* keys  = (const float*)d_in[1];  // (4,512,512)
    const float* W1    = (const float*)d_in[2];  // (128,512)
    const float* W2    = (const float*)d_in[3];  // (128,512)
    const float* v     = (const float*)d_in[4];  // (1,256)
    float* out = (float*)d_out;                  // (4,512,512) f32
    float* ws  = (float*)d_ws;                   // a' + c' (4096 floats)

    proj_kernel<<<256, 512, 0, stream>>>(query, keys, W1, W2, v, ws);
    outer_kernel<<<256, 256, 0, stream>>>(ws, out);
}